// Round 1
// baseline (1177.982 us; speedup 1.0000x reference)
//
#include <hip/hip_runtime.h>
#include <math.h>

#define DD    128
#define DFF   256
#define NHH   4
#define HDD   32
#define BB    8
#define TT    1024
#define NTOK  (BB*TT)          // 8192
#define KSPLIT 4
#define KCH   (TT/KSPLIT)      // 256

// ---------------- wave helpers (wave64) ----------------
__device__ __forceinline__ float wsum(float v){
#pragma unroll
  for(int o=32;o>0;o>>=1) v += __shfl_xor(v,o,64);
  return v;
}
__device__ __forceinline__ float wmaxr(float v){
#pragma unroll
  for(int o=32;o>0;o>>=1) v = fmaxf(v,__shfl_xor(v,o,64));
  return v;
}

// ---------------- LayerNorm: one wave per token ----------------
// g==nullptr -> plain normalize (xn)
__global__ __launch_bounds__(256) void ln_kernel(const float* __restrict__ in,
                                                 float* __restrict__ out,
                                                 const float* __restrict__ g,
                                                 const float* __restrict__ b){
  int lane = threadIdx.x & 63;
  int t = (blockIdx.x<<2) + (threadIdx.x>>6);
  const float* row = in + (size_t)t*DD;
  float x0 = row[lane], x1 = row[lane+64];
  float m = wsum(x0+x1) * (1.0f/DD);
  float d0 = x0-m, d1 = x1-m;
  float v = wsum(d0*d0 + d1*d1) * (1.0f/DD);
  float r = rsqrtf(v + 1e-5f);
  float y0 = d0*r, y1 = d1*r;
  if(g){ y0 = y0*g[lane] + b[lane]; y1 = y1*g[lane+64] + b[lane+64]; }
  out[(size_t)t*DD+lane]    = y0;
  out[(size_t)t*DD+lane+64] = y1;
}

// ---------------- routing: one wave per token ----------------
__global__ __launch_bounds__(256) void routing_kernel(
    const float* __restrict__ xn,
    const float* __restrict__ gr_g, const float* __restrict__ gr_b,
    const float* __restrict__ q6,   const float* __restrict__ logtemp,
    const float* __restrict__ grp_g,const float* __restrict__ grp_b,
    const float* __restrict__ gpw,  const float* __restrict__ gpb,
    float* __restrict__ gw_out, float* __restrict__ coef, float* __restrict__ part){
  __shared__ float sp[4][9];
  int lane = threadIdx.x & 63;
  int wv   = threadIdx.x >> 6;
  int t    = (blockIdx.x<<2) + wv;
  const float* xr = xn + (size_t)t*DD;
  float x0 = xr[lane], x1 = xr[lane+64];
  float h0 = x0*gr_g[lane]+gr_b[lane];
  float h1 = x1*gr_g[lane+64]+gr_b[lane+64];
  float sb[6];
#pragma unroll
  for(int j=0;j<6;j++){
    float p = h0*q6[j*DD+lane] + h1*q6[j*DD+lane+64];
    sb[j] = tanhf(wsum(p));
  }
  // lane n = hex code index; hex(n,j) = ((n>>(5-j))&1)?+1:-1
  float sim = 0.f;
#pragma unroll
  for(int j=0;j<6;j++) sim += ((lane>>(5-j))&1) ? sb[j] : -sb[j];
  float temp = expf(logtemp[0]); temp = fminf(fmaxf(temp,0.1f),5.0f);
  float mx = wmaxr(sim);
  float p  = expf((sim-mx)/temp);
  float w  = p / wsum(p);
  float sh[6];
#pragma unroll
  for(int j=0;j<6;j++) sh[j] = wsum(((lane>>(5-j))&1) ? w : -w);
  const float A0[6]={0,1,1,0,1,1}, A1[6]={0,-1,0,1,0,0}, A2[6]={-1,0,-1,-1,0,-1};
  float l0=0,l1=0,l2=0;
#pragma unroll
  for(int j=0;j<6;j++){ l0+=sh[j]*A0[j]; l1+=sh[j]*A1[j]; l2+=sh[j]*A2[j]; }
  float m3 = fmaxf(l0,fmaxf(l1,l2));
  float e0=expf(l0-m3), e1=expf(l1-m3), e2=expf(l2-m3);
  float inv3 = 1.0f/(e0+e1+e2);
  float g0=e0*inv3, g1=e1*inv3, g2=e2*inv3;
  if(lane==0){ gw_out[t*3]=g0; gw_out[t*3+1]=g1; gw_out[t*3+2]=g2; }
  float gwv[3]={g0,g1,g2};
  float pw[6];
#pragma unroll
  for(int g=0; g<3; g++){
    float hg0 = x0*grp_g[g*DD+lane]    + grp_b[g*DD+lane];
    float hg1 = x1*grp_g[g*DD+lane+64] + grp_b[g*DD+lane+64];
    float q0 = wsum(hg0*gpw[(g*2+0)*DD+lane] + hg1*gpw[(g*2+0)*DD+lane+64]) + gpb[g*2+0];
    float q1 = wsum(hg0*gpw[(g*2+1)*DD+lane] + hg1*gpw[(g*2+1)*DD+lane+64]) + gpb[g*2+1];
    float mm = fmaxf(q0,q1);
    float a0 = expf(q0-mm), a1 = expf(q1-mm);
    float inv = 1.0f/(a0+a1);
    float w0 = a0*inv, w1 = a1*inv;
    pw[g*2]=w0; pw[g*2+1]=w1;
    float invs = 1.0f/(w0+w1+1e-8f);
    if(lane==0){
      coef[(size_t)(2*g  )*NTOK + t] = gwv[g]*w0*invs;
      coef[(size_t)(2*g+1)*NTOK + t] = gwv[g]*w1*invs;
    }
  }
  if(lane==0){
    sp[wv][0]=g0; sp[wv][1]=g1; sp[wv][2]=g2;
#pragma unroll
    for(int k=0;k<6;k++) sp[wv][3+k]=pw[k];
  }
  __syncthreads();
  if(threadIdx.x<9){
    part[blockIdx.x*9+threadIdx.x] =
      sp[0][threadIdx.x]+sp[1][threadIdx.x]+sp[2][threadIdx.x]+sp[3][threadIdx.x];
  }
}

// ---------------- load-balance loss reduce (deterministic) ----------------
__global__ void lb_kernel(const float* __restrict__ part, float* __restrict__ outlb){
  __shared__ float sums[9];
  int c = threadIdx.x;
  if(c<9){
    float s=0;
    for(int i=0;i<2048;i++) s += part[i*9+c];
    sums[c]=s;
  }
  __syncthreads();
  if(threadIdx.x==0){
    const float invN = 1.0f/(float)NTOK;
    float lb=0;
    for(int k=0;k<9;k++){ float mw = sums[k]*invN; lb -= mw*logf(mw+1e-8f); }
    outlb[0] = lb*0.01f;
  }
}

// ---------------- tiled fp32 GEMM: C[M,N] = epilogue(A[M,K] @ W[N,K]^T) ----------------
// MODE 0: store  1: silu(acc)*vbuf  2: rowv[m]*acc (+C if ADD)  3: resid+acc  4: C += BW*sigmoid(*gptr)*(resid+acc)
template<int MODE, int ADD>
__global__ __launch_bounds__(256) void gemm64(
    const float* __restrict__ A, const float* __restrict__ W, float* __restrict__ C,
    int M, int N, int K,
    const float* __restrict__ svec, const float* __restrict__ bvec,
    const float* __restrict__ vbuf, const float* __restrict__ rowv,
    const float* __restrict__ resid,const float* __restrict__ gptr){
  __shared__ float As[32][68];
  __shared__ float Ws[32][68];
  int tid = threadIdx.x;
  int tx = tid & 15, ty = tid >> 4;
  int m0 = blockIdx.y*64, n0 = blockIdx.x*64;
  float acc[4][4] = {};
  const bool hasSB = (svec != nullptr);
  for(int k0=0;k0<K;k0+=32){
#pragma unroll
    for(int l=0;l<2;l++){
      int idx = tid + l*256;
      int r = idx >> 3;
      int c4 = idx & 7;
      float4 a = *reinterpret_cast<const float4*>(&A[(size_t)(m0+r)*K + k0 + c4*4]);
      if(hasSB){
        int kk = k0 + c4*4;
        a.x = a.x*svec[kk  ]+bvec[kk  ];
        a.y = a.y*svec[kk+1]+bvec[kk+1];
        a.z = a.z*svec[kk+2]+bvec[kk+2];
        a.w = a.w*svec[kk+3]+bvec[kk+3];
      }
      As[c4*4+0][r]=a.x; As[c4*4+1][r]=a.y; As[c4*4+2][r]=a.z; As[c4*4+3][r]=a.w;
      float4 wv = *reinterpret_cast<const float4*>(&W[(size_t)(n0+r)*K + k0 + c4*4]);
      Ws[c4*4+0][r]=wv.x; Ws[c4*4+1][r]=wv.y; Ws[c4*4+2][r]=wv.z; Ws[c4*4+3][r]=wv.w;
    }
    __syncthreads();
#pragma unroll
    for(int kk=0;kk<32;kk++){
      float4 a = *reinterpret_cast<const float4*>(&As[kk][ty*4]);
      float4 b = *reinterpret_cast<const float4*>(&Ws[kk][tx*4]);
      float av[4]={a.x,a.y,a.z,a.w}, bv[4]={b.x,b.y,b.z,b.w};
#pragma unroll
      for(int i=0;i<4;i++)
#pragma unroll
        for(int j=0;j<4;j++) acc[i][j] += av[i]*bv[j];
    }
    __syncthreads();
  }
#pragma unroll
  for(int i=0;i<4;i++){
    int m = m0 + ty*4 + i;
#pragma unroll
    for(int j=0;j<4;j++){
      int n = n0 + tx*4 + j;
      float v = acc[i][j];
      size_t o = (size_t)m*N + n;
      if(MODE==0){ C[o] = v; }
      else if(MODE==1){ float sg = v/(1.0f+expf(-v)); C[o] = sg * vbuf[o]; }
      else if(MODE==2){ float r = rowv[m]*v; C[o] = ADD ? (C[o]+r) : r; }
      else if(MODE==3){ C[o] = resid[o] + v; }
      else if(MODE==4){
        float gs = (0.5f/3.0f)/(1.0f+expf(-gptr[0]));
        C[o] += gs*(resid[o]+v);
      }
    }
  }
}

// ---------------- attention partial (K-split flash, per-thread q row) ----------------
__global__ __launch_bounds__(256) void attn_partial(
    const float* __restrict__ Qb, const float* __restrict__ KVb,
    float* __restrict__ opart, float* __restrict__ mpart, float* __restrict__ lpart){
  int tid = threadIdx.x;
  int row = blockIdx.x*256 + tid;     // token index 0..8191 (b uniform per block)
  int b   = blockIdx.x >> 2;          // 4 blocks.x per batch
  int h   = blockIdx.y;
  int sp  = blockIdx.z;
  const float scale = 0.17677669529663687f;   // 1/sqrt(32)
  float q[HDD];
  const float* qrow = Qb + (size_t)row*DD + h*HDD;
#pragma unroll
  for(int d=0;d<HDD;d++) q[d] = qrow[d]*scale;
  const float* Kp = KVb + ((size_t)(b*TT + sp*KCH))*(2*DD) + h*HDD;   // block-uniform
  float mx = -1e30f;
  for(int kk=0;kk<KCH;kk++){
    const float* kr = Kp + (size_t)kk*(2*DD);
    float s=0;
#pragma unroll
    for(int d=0;d<HDD;d++) s += q[d]*kr[d];
    mx = fmaxf(mx,s);
  }
  float l=0;
  float o[HDD];
#pragma unroll
  for(int d=0;d<HDD;d++) o[d]=0.f;
  for(int kk=0;kk<KCH;kk++){
    const float* kr = Kp + (size_t)kk*(2*DD);
    const float* vr = kr + DD;
    float s=0;
#pragma unroll
    for(int d=0;d<HDD;d++) s += q[d]*kr[d];
    float p = expf(s-mx);
    l += p;
#pragma unroll
    for(int d=0;d<HDD;d++) o[d] += p*vr[d];
  }
  float* op = opart + ((size_t)sp*NTOK + row)*DD + h*HDD;
#pragma unroll
  for(int d=0;d<HDD;d++) op[d] = o[d];
  mpart[((size_t)sp*NTOK+row)*NHH + h] = mx;
  lpart[((size_t)sp*NTOK+row)*NHH + h] = l;
}

__global__ __launch_bounds__(256) void attn_merge(
    const float* __restrict__ opart, const float* __restrict__ mpart,
    const float* __restrict__ lpart, float* __restrict__ O){
  int idx = blockIdx.x*256 + threadIdx.x;  // row*NH + h
  if(idx >= NTOK*NHH) return;
  int row = idx >> 2, h = idx & 3;
  float mv[KSPLIT], lv[KSPLIT];
  float M = -1e30f;
#pragma unroll
  for(int s=0;s<KSPLIT;s++){
    mv[s] = mpart[((size_t)s*NTOK+row)*NHH + h];
    lv[s] = lpart[((size_t)s*NTOK+row)*NHH + h];
    M = fmaxf(M, mv[s]);
  }
  float f[KSPLIT]; float l=0;
#pragma unroll
  for(int s=0;s<KSPLIT;s++){ f[s] = expf(mv[s]-M); l += lv[s]*f[s]; }
  float invl = 1.0f/l;
  float* orow = O + (size_t)row*DD + h*HDD;
#pragma unroll
  for(int d=0;d<HDD;d++){
    float acc=0;
#pragma unroll
    for(int s=0;s<KSPLIT;s++) acc += opart[((size_t)s*NTOK+row)*DD + h*HDD + d]*f[s];
    orow[d] = acc*invl;
  }
}

__global__ __launch_bounds__(256) void add3_kernel(const float* __restrict__ a,
                                                   const float* __restrict__ b,
                                                   const float* __restrict__ c,
                                                   float* __restrict__ out, int n){
  int i = blockIdx.x*256 + threadIdx.x;
  if(i<n) out[i] = a[i]+b[i]+c[i];
}

// ---------------- launch ----------------
extern "C" void kernel_launch(void* const* d_in, const int* in_sizes, int n_in,
                              void* d_out, int out_size, void* d_ws, size_t ws_size,
                              hipStream_t stream){
  (void)in_sizes; (void)n_in; (void)out_size; (void)ws_size;
  const float* x       = (const float*)d_in[0];
  const float* gr_g    = (const float*)d_in[1];
  const float* gr_b    = (const float*)d_in[2];
  const float* q6_w    = (const float*)d_in[3];
  const float* logtemp = (const float*)d_in[4];
  const float* grp_g   = (const float*)d_in[5];
  const float* grp_b   = (const float*)d_in[6];
  const float* gpw     = (const float*)d_in[7];
  const float* gpb     = (const float*)d_in[8];
  const float* me_g    = (const float*)d_in[9];
  const float* me_b    = (const float*)d_in[10];
  const float* me_gate = (const float*)d_in[11];
  const float* me_val  = (const float*)d_in[12];
  const float* me_out  = (const float*)d_in[13];
  const float* br_in   = (const float*)d_in[14];
  const float* br_outw = (const float*)d_in[15];
  const float* nq_g    = (const float*)d_in[16];
  const float* nq_b    = (const float*)d_in[17];
  const float* nkv_g   = (const float*)d_in[18];
  const float* nkv_b   = (const float*)d_in[19];
  const float* nff_g   = (const float*)d_in[20];
  const float* nff_b   = (const float*)d_in[21];
  const float* brg_w   = (const float*)d_in[22];
  const float* brv_w   = (const float*)d_in[23];
  const float* brf_w   = (const float*)d_in[24];
  const float* br_gate = (const float*)d_in[25];
  const float* on_g    = (const float*)d_in[26];
  const float* on_b    = (const float*)d_in[27];
  const float* out_w   = (const float*)d_in[28];
  float* out = (float*)d_out;
  float* ws  = (float*)d_ws;

  float* xn    = ws;                 // 1048576
  float* gw    = ws + 1048576;       // 24576
  float* coef  = ws + 1073152;       // 49152
  float* part  = ws + 1122304;       // 18432
  float* vbuf  = ws + 1140736;       // 2097152
  float* gvb   = ws + 3237888;       // 2097152
  float* go    = ws + 5335040;       // 3*1048576
  float* qn    = ws + 8480768;       // 1048576
  float* kvn   = ws + 9529344;       // 1048576
  float* Qb    = ws + 10577920;      // 1048576
  float* KVb   = ws + 11626496;      // 2097152
  float* opart = ws + 13723648;      // 4194304
  float* mpart = ws + 17917952;      // 131072
  float* lpart = ws + 18049024;      // 131072
  float* obuf  = ws + 18180096;      // 1048576
  float* xb    = ws + 19228672;      // 1048576
  float* hb    = ws + 20277248;      // 1048576
  float* comb  = ws + 21325824;      // 1048576

  // 1. xn (plain normalize) + routing + lb
  ln_kernel<<<2048,256,0,stream>>>(x, xn, nullptr, nullptr);
  routing_kernel<<<2048,256,0,stream>>>(xn, gr_g, gr_b, q6_w, logtemp,
                                        grp_g, grp_b, gpw, gpb, gw, coef, part);
  lb_kernel<<<1,64,0,stream>>>(part, out + 1048576);

  // 2. MoE experts -> group_outs (go)
  for(int e=0;e<6;e++){
    gemm64<0,0><<<dim3(4,128),256,0,stream>>>(xn, me_val + (size_t)e*DFF*DD, vbuf,
        NTOK,DFF,DD, me_g+e*DD, me_b+e*DD, nullptr,nullptr,nullptr,nullptr);
    gemm64<1,0><<<dim3(4,128),256,0,stream>>>(xn, me_gate + (size_t)e*DFF*DD, gvb,
        NTOK,DFF,DD, me_g+e*DD, me_b+e*DD, vbuf,nullptr,nullptr,nullptr);
    float* gout = go + (size_t)(e>>1)*NTOK*DD;
    if(e&1)
      gemm64<2,1><<<dim3(2,128),256,0,stream>>>(gvb, me_out + (size_t)e*DD*DFF, gout,
          NTOK,DD,DFF, nullptr,nullptr,nullptr, coef+(size_t)e*NTOK, nullptr,nullptr);
    else
      gemm64<2,0><<<dim3(2,128),256,0,stream>>>(gvb, me_out + (size_t)e*DD*DFF, gout,
          NTOK,DD,DFF, nullptr,nullptr,nullptr, coef+(size_t)e*NTOK, nullptr,nullptr);
  }

  // 3. combined = go0+go1+go2
  add3_kernel<<<4096,256,0,stream>>>(go, go+(size_t)NTOK*DD, go+(size_t)2*NTOK*DD, comb, NTOK*DD);

  // 4. bridges
  const int pairs[3][2] = {{0,1},{1,2},{0,2}};
  for(int i=0;i<3;i++){
    const float* xq = go + (size_t)pairs[i][0]*NTOK*DD;
    const float* xk = go + (size_t)pairs[i][1]*NTOK*DD;
    ln_kernel<<<2048,256,0,stream>>>(xq, qn,  nq_g+i*DD,  nq_b+i*DD);
    ln_kernel<<<2048,256,0,stream>>>(xk, kvn, nkv_g+i*DD, nkv_b+i*DD);
    gemm64<0,0><<<dim3(2,128),256,0,stream>>>(qn,  br_in + (size_t)i*3*DD*DD, Qb,
        NTOK,DD,DD, nullptr,nullptr,nullptr,nullptr,nullptr,nullptr);
    gemm64<0,0><<<dim3(4,128),256,0,stream>>>(kvn, br_in + (size_t)i*3*DD*DD + DD*DD, KVb,
        NTOK,2*DD,DD, nullptr,nullptr,nullptr,nullptr,nullptr,nullptr);
    attn_partial<<<dim3(32,NHH,KSPLIT),256,0,stream>>>(Qb, KVb, opart, mpart, lpart);
    attn_merge<<<128,256,0,stream>>>(opart, mpart, lpart, obuf);
    gemm64<3,0><<<dim3(2,128),256,0,stream>>>(obuf, br_outw + (size_t)i*DD*DD, xb,
        NTOK,DD,DD, nullptr,nullptr,nullptr,nullptr, xq, nullptr);
    ln_kernel<<<2048,256,0,stream>>>(xb, hb, nff_g+i*DD, nff_b+i*DD);
    gemm64<0,0><<<dim3(4,128),256,0,stream>>>(hb, brv_w + (size_t)i*2*DD*DD, vbuf,
        NTOK,2*DD,DD, nullptr,nullptr,nullptr,nullptr,nullptr,nullptr);
    gemm64<1,0><<<dim3(4,128),256,0,stream>>>(hb, brg_w + (size_t)i*2*DD*DD, gvb,
        NTOK,2*DD,DD, nullptr,nullptr, vbuf,nullptr,nullptr,nullptr);
    gemm64<4,0><<<dim3(2,128),256,0,stream>>>(gvb, brf_w + (size_t)i*DD*2*DD, comb,
        NTOK,DD,2*DD, nullptr,nullptr,nullptr,nullptr, xb, br_gate+i);
  }

  // 5. final LN + projection
  ln_kernel<<<2048,256,0,stream>>>(comb, hb, on_g, on_b);
  gemm64<0,0><<<dim3(2,128),256,0,stream>>>(hb, out_w, out,
      NTOK,DD,DD, nullptr,nullptr,nullptr,nullptr,nullptr,nullptr);
}

// Round 2
// 929.846 us; speedup vs baseline: 1.2669x; 1.2669x over previous
//
#include <hip/hip_runtime.h>
#include <math.h>

#define DD    128
#define DFF   256
#define NHH   4
#define HDD   32
#define BB    8
#define TT    1024
#define NTOK  (BB*TT)          // 8192
#define KSPLIT 4
#define KCH   (TT/KSPLIT)      // 256
#define AKEYS 64               // keys per LDS tile

// ---------------- wave helpers (wave64) ----------------
__device__ __forceinline__ float wsum(float v){
#pragma unroll
  for(int o=32;o>0;o>>=1) v += __shfl_xor(v,o,64);
  return v;
}
__device__ __forceinline__ float wmaxr(float v){
#pragma unroll
  for(int o=32;o>0;o>>=1) v = fmaxf(v,__shfl_xor(v,o,64));
  return v;
}

// ---------------- LayerNorm: one wave per token ----------------
__global__ __launch_bounds__(256) void ln_kernel(const float* __restrict__ in,
                                                 float* __restrict__ out,
                                                 const float* __restrict__ g,
                                                 const float* __restrict__ b){
  int lane = threadIdx.x & 63;
  int t = (blockIdx.x<<2) + (threadIdx.x>>6);
  const float* row = in + (size_t)t*DD;
  float x0 = row[lane], x1 = row[lane+64];
  float m = wsum(x0+x1) * (1.0f/DD);
  float d0 = x0-m, d1 = x1-m;
  float v = wsum(d0*d0 + d1*d1) * (1.0f/DD);
  float r = rsqrtf(v + 1e-5f);
  float y0 = d0*r, y1 = d1*r;
  if(g){ y0 = y0*g[lane] + b[lane]; y1 = y1*g[lane+64] + b[lane+64]; }
  out[(size_t)t*DD+lane]    = y0;
  out[(size_t)t*DD+lane+64] = y1;
}

// ---------------- routing: one wave per token ----------------
__global__ __launch_bounds__(256) void routing_kernel(
    const float* __restrict__ xn,
    const float* __restrict__ gr_g, const float* __restrict__ gr_b,
    const float* __restrict__ q6,   const float* __restrict__ logtemp,
    const float* __restrict__ grp_g,const float* __restrict__ grp_b,
    const float* __restrict__ gpw,  const float* __restrict__ gpb,
    float* __restrict__ gw_out, float* __restrict__ coef, float* __restrict__ part){
  __shared__ float sp[4][9];
  int lane = threadIdx.x & 63;
  int wv   = threadIdx.x >> 6;
  int t    = (blockIdx.x<<2) + wv;
  const float* xr = xn + (size_t)t*DD;
  float x0 = xr[lane], x1 = xr[lane+64];
  float h0 = x0*gr_g[lane]+gr_b[lane];
  float h1 = x1*gr_g[lane+64]+gr_b[lane+64];
  float sb[6];
#pragma unroll
  for(int j=0;j<6;j++){
    float p = h0*q6[j*DD+lane] + h1*q6[j*DD+lane+64];
    sb[j] = tanhf(wsum(p));
  }
  float sim = 0.f;
#pragma unroll
  for(int j=0;j<6;j++) sim += ((lane>>(5-j))&1) ? sb[j] : -sb[j];
  float temp = expf(logtemp[0]); temp = fminf(fmaxf(temp,0.1f),5.0f);
  float mx = wmaxr(sim);
  float p  = expf((sim-mx)/temp);
  float w  = p / wsum(p);
  float sh[6];
#pragma unroll
  for(int j=0;j<6;j++) sh[j] = wsum(((lane>>(5-j))&1) ? w : -w);
  const float A0[6]={0,1,1,0,1,1}, A1[6]={0,-1,0,1,0,0}, A2[6]={-1,0,-1,-1,0,-1};
  float l0=0,l1=0,l2=0;
#pragma unroll
  for(int j=0;j<6;j++){ l0+=sh[j]*A0[j]; l1+=sh[j]*A1[j]; l2+=sh[j]*A2[j]; }
  float m3 = fmaxf(l0,fmaxf(l1,l2));
  float e0=expf(l0-m3), e1=expf(l1-m3), e2=expf(l2-m3);
  float inv3 = 1.0f/(e0+e1+e2);
  float g0=e0*inv3, g1=e1*inv3, g2=e2*inv3;
  if(lane==0){ gw_out[t*3]=g0; gw_out[t*3+1]=g1; gw_out[t*3+2]=g2; }
  float gwv[3]={g0,g1,g2};
  float pw[6];
#pragma unroll
  for(int g=0; g<3; g++){
    float hg0 = x0*grp_g[g*DD+lane]    + grp_b[g*DD+lane];
    float hg1 = x1*grp_g[g*DD+lane+64] + grp_b[g*DD+lane+64];
    float q0 = wsum(hg0*gpw[(g*2+0)*DD+lane] + hg1*gpw[(g*2+0)*DD+lane+64]) + gpb[g*2+0];
    float q1 = wsum(hg0*gpw[(g*2+1)*DD+lane] + hg1*gpw[(g*2+1)*DD+lane+64]) + gpb[g*2+1];
    float mm = fmaxf(q0,q1);
    float a0 = expf(q0-mm), a1 = expf(q1-mm);
    float inv = 1.0f/(a0+a1);
    float w0 = a0*inv, w1 = a1*inv;
    pw[g*2]=w0; pw[g*2+1]=w1;
    float invs = 1.0f/(w0+w1+1e-8f);
    if(lane==0){
      coef[(size_t)(2*g  )*NTOK + t] = gwv[g]*w0*invs;
      coef[(size_t)(2*g+1)*NTOK + t] = gwv[g]*w1*invs;
    }
  }
  if(lane==0){
    sp[wv][0]=g0; sp[wv][1]=g1; sp[wv][2]=g2;
#pragma unroll
    for(int k=0;k<6;k++) sp[wv][3+k]=pw[k];
  }
  __syncthreads();
  if(threadIdx.x<9){
    part[blockIdx.x*9+threadIdx.x] =
      sp[0][threadIdx.x]+sp[1][threadIdx.x]+sp[2][threadIdx.x]+sp[3][threadIdx.x];
  }
}

// ---------------- load-balance loss reduce (deterministic) ----------------
__global__ void lb_kernel(const float* __restrict__ part, float* __restrict__ outlb){
  __shared__ float sums[9];
  int c = threadIdx.x;
  if(c<9){
    float s=0;
    for(int i=0;i<2048;i++) s += part[i*9+c];
    sums[c]=s;
  }
  __syncthreads();
  if(threadIdx.x==0){
    const float invN = 1.0f/(float)NTOK;
    float lb=0;
    for(int k=0;k<9;k++){ float mw = sums[k]*invN; lb -= mw*logf(mw+1e-8f); }
    outlb[0] = lb*0.01f;
  }
}

// ---------------- tiled fp32 GEMM: C[M,N] = epilogue(A[M,K] @ W[N,K]^T) ----------------
// MODE 0: store  1: silu(acc)*vbuf  2: rowv[m]*acc (+C if ADD)  3: resid+acc  4: C += BW*sigmoid(*gptr)*(resid+acc)
template<int MODE, int ADD>
__global__ __launch_bounds__(256) void gemm64(
    const float* __restrict__ A, const float* __restrict__ W, float* __restrict__ C,
    int M, int N, int K,
    const float* __restrict__ svec, const float* __restrict__ bvec,
    const float* __restrict__ vbuf, const float* __restrict__ rowv,
    const float* __restrict__ resid,const float* __restrict__ gptr){
  __shared__ float As[32][68];
  __shared__ float Ws[32][68];
  int tid = threadIdx.x;
  int tx = tid & 15, ty = tid >> 4;
  int m0 = blockIdx.y*64, n0 = blockIdx.x*64;
  float acc[4][4] = {};
  const bool hasSB = (svec != nullptr);
  for(int k0=0;k0<K;k0+=32){
#pragma unroll
    for(int l=0;l<2;l++){
      int idx = tid + l*256;
      int r = idx >> 3;
      int c4 = idx & 7;
      float4 a = *reinterpret_cast<const float4*>(&A[(size_t)(m0+r)*K + k0 + c4*4]);
      if(hasSB){
        int kk = k0 + c4*4;
        a.x = a.x*svec[kk  ]+bvec[kk  ];
        a.y = a.y*svec[kk+1]+bvec[kk+1];
        a.z = a.z*svec[kk+2]+bvec[kk+2];
        a.w = a.w*svec[kk+3]+bvec[kk+3];
      }
      As[c4*4+0][r]=a.x; As[c4*4+1][r]=a.y; As[c4*4+2][r]=a.z; As[c4*4+3][r]=a.w;
      float4 wv = *reinterpret_cast<const float4*>(&W[(size_t)(n0+r)*K + k0 + c4*4]);
      Ws[c4*4+0][r]=wv.x; Ws[c4*4+1][r]=wv.y; Ws[c4*4+2][r]=wv.z; Ws[c4*4+3][r]=wv.w;
    }
    __syncthreads();
#pragma unroll
    for(int kk=0;kk<32;kk++){
      float4 a = *reinterpret_cast<const float4*>(&As[kk][ty*4]);
      float4 b = *reinterpret_cast<const float4*>(&Ws[kk][tx*4]);
      float av[4]={a.x,a.y,a.z,a.w}, bv[4]={b.x,b.y,b.z,b.w};
#pragma unroll
      for(int i=0;i<4;i++)
#pragma unroll
        for(int j=0;j<4;j++) acc[i][j] += av[i]*bv[j];
    }
    __syncthreads();
  }
#pragma unroll
  for(int i=0;i<4;i++){
    int m = m0 + ty*4 + i;
#pragma unroll
    for(int j=0;j<4;j++){
      int n = n0 + tx*4 + j;
      float v = acc[i][j];
      size_t o = (size_t)m*N + n;
      if(MODE==0){ C[o] = v; }
      else if(MODE==1){ float sg = v/(1.0f+expf(-v)); C[o] = sg * vbuf[o]; }
      else if(MODE==2){ float r = rowv[m]*v; C[o] = ADD ? (C[o]+r) : r; }
      else if(MODE==3){ C[o] = resid[o] + v; }
      else if(MODE==4){
        float gs = (0.5f/3.0f)/(1.0f+expf(-gptr[0]));
        C[o] += gs*(resid[o]+v);
      }
    }
  }
}

// ---------------- attention partial: LDS-staged K/V, online softmax ----------------
// block: 256 threads = 256 q-rows; (b,h,split) uniform per block.
// K/V tile (AKEYS keys) staged in LDS; single pass, deferred wave-voted rescale.
__global__ __launch_bounds__(256) void attn_partial(
    const float* __restrict__ Qb, const float* __restrict__ KVb,
    float* __restrict__ opart, float* __restrict__ mpart, float* __restrict__ lpart){
  __shared__ float Ks[AKEYS][HDD];   // 8 KB
  __shared__ float Vs[AKEYS][HDD];   // 8 KB
  int tid = threadIdx.x;
  int row = blockIdx.x*256 + tid;
  int b   = blockIdx.x >> 2;
  int h   = blockIdx.y;
  int sp  = blockIdx.z;
  const float scale = 0.17677669529663687f;   // 1/sqrt(32)
  float q[HDD];
  const float* qrow = Qb + (size_t)row*DD + h*HDD;
#pragma unroll
  for(int d=0;d<HDD;d++) q[d] = qrow[d]*scale;
  float M = -1e30f, l = 0.f;
  float o[HDD];
#pragma unroll
  for(int d=0;d<HDD;d++) o[d]=0.f;
  // per-key KV row stride = 2*DD floats; K slice at +0, V slice at +DD (both h-offset)
  const float* KVbase = KVb + ((size_t)(b*TT + sp*KCH))*(2*DD) + h*HDD;

  for(int t0=0; t0<KCH; t0+=AKEYS){
    __syncthreads();
    // cooperative stage: AKEYS keys x 16 float4 (8 K + 8 V) = 1024 float4; 4 per thread
#pragma unroll
    for(int l4=0; l4<4; l4++){
      int idx  = tid + l4*256;        // 0..1023
      int key  = idx >> 4;
      int part = idx & 15;
      const float4 v = *reinterpret_cast<const float4*>(
          KVbase + (size_t)(t0+key)*(2*DD) + (part<8 ? part*4 : DD + (part-8)*4));
      if(part<8) *reinterpret_cast<float4*>(&Ks[key][part*4])     = v;
      else       *reinterpret_cast<float4*>(&Vs[key][(part-8)*4]) = v;
    }
    __syncthreads();
#pragma unroll 2
    for(int kk=0; kk<AKEYS; kk++){
      float s = 0.f;
#pragma unroll
      for(int d=0;d<HDD;d++) s += q[d]*Ks[kk][d];
      // deferred rescale: only when some lane's score exceeds M+8 (wave-uniform branch)
      if(__any(s > M + 8.0f)){
        float mn = fmaxf(M, s);
        float sc = expf(M - mn);
        l *= sc;
#pragma unroll
        for(int d=0;d<HDD;d++) o[d] *= sc;
        M = mn;
      }
      float p = expf(s - M);
      l += p;
#pragma unroll
      for(int d=0;d<HDD;d++) o[d] += p*Vs[kk][d];
    }
  }
  float* op = opart + ((size_t)sp*NTOK + row)*DD + h*HDD;
#pragma unroll
  for(int d=0;d<HDD;d++) op[d] = o[d];
  mpart[((size_t)sp*NTOK+row)*NHH + h] = M;
  lpart[((size_t)sp*NTOK+row)*NHH + h] = l;
}

__global__ __launch_bounds__(256) void attn_merge(
    const float* __restrict__ opart, const float* __restrict__ mpart,
    const float* __restrict__ lpart, float* __restrict__ O){
  int idx = blockIdx.x*256 + threadIdx.x;  // row*NH + h
  if(idx >= NTOK*NHH) return;
  int row = idx >> 2, h = idx & 3;
  float mv[KSPLIT], lv[KSPLIT];
  float M = -1e30f;
#pragma unroll
  for(int s=0;s<KSPLIT;s++){
    mv[s] = mpart[((size_t)s*NTOK+row)*NHH + h];
    lv[s] = lpart[((size_t)s*NTOK+row)*NHH + h];
    M = fmaxf(M, mv[s]);
  }
  float f[KSPLIT]; float l=0;
#pragma unroll
  for(int s=0;s<KSPLIT;s++){ f[s] = expf(mv[s]-M); l += lv[s]*f[s]; }
  float invl = 1.0f/l;
  float* orow = O + (size_t)row*DD + h*HDD;
#pragma unroll
  for(int d=0;d<HDD;d++){
    float acc=0;
#pragma unroll
    for(int s=0;s<KSPLIT;s++) acc += opart[((size_t)s*NTOK+row)*DD + h*HDD + d]*f[s];
    orow[d] = acc*invl;
  }
}

__global__ __launch_bounds__(256) void add3_kernel(const float* __restrict__ a,
                                                   const float* __restrict__ b,
                                                   const float* __restrict__ c,
                                                   float* __restrict__ out, int n){
  int i = blockIdx.x*256 + threadIdx.x;
  if(i<n) out[i] = a[i]+b[i]+c[i];
}

// ---------------- launch ----------------
extern "C" void kernel_launch(void* const* d_in, const int* in_sizes, int n_in,
                              void* d_out, int out_size, void* d_ws, size_t ws_size,
                              hipStream_t stream){
  (void)in_sizes; (void)n_in; (void)out_size; (void)ws_size;
  const float* x       = (const float*)d_in[0];
  const float* gr_g    = (const float*)d_in[1];
  const float* gr_b    = (const float*)d_in[2];
  const float* q6_w    = (const float*)d_in[3];
  const float* logtemp = (const float*)d_in[4];
  const float* grp_g   = (const float*)d_in[5];
  const float* grp_b   = (const float*)d_in[6];
  const float* gpw     = (const float*)d_in[7];
  const float* gpb     = (const float*)d_in[8];
  const float* me_g    = (const float*)d_in[9];
  const float* me_b    = (const float*)d_in[10];
  const float* me_gate = (const float*)d_in[11];
  const float* me_val  = (const float*)d_in[12];
  const float* me_out  = (const float*)d_in[13];
  const float* br_in   = (const float*)d_in[14];
  const float* br_outw = (const float*)d_in[15];
  const float* nq_g    = (const float*)d_in[16];
  const float* nq_b    = (const float*)d_in[17];
  const float* nkv_g   = (const float*)d_in[18];
  const float* nkv_b   = (const float*)d_in[19];
  const float* nff_g   = (const float*)d_in[20];
  const float* nff_b   = (const float*)d_in[21];
  const float* brg_w   = (const float*)d_in[22];
  const float* brv_w   = (const float*)d_in[23];
  const float* brf_w   = (const float*)d_in[24];
  const float* br_gate = (const float*)d_in[25];
  const float* on_g    = (const float*)d_in[26];
  const float* on_b    = (const float*)d_in[27];
  const float* out_w   = (const float*)d_in[28];
  float* out = (float*)d_out;
  float* ws  = (float*)d_ws;

  float* xn    = ws;                 // 1048576
  float* gw    = ws + 1048576;       // 24576
  float* coef  = ws + 1073152;       // 49152
  float* part  = ws + 1122304;       // 18432
  float* vbuf  = ws + 1140736;       // 2097152
  float* gvb   = ws + 3237888;       // 2097152
  float* go    = ws + 5335040;       // 3*1048576
  float* qn    = ws + 8480768;       // 1048576
  float* kvn   = ws + 9529344;       // 1048576
  float* Qb    = ws + 10577920;      // 1048576
  float* KVb   = ws + 11626496;      // 2097152
  float* opart = ws + 13723648;      // 4194304
  float* mpart = ws + 17917952;      // 131072
  float* lpart = ws + 18049024;      // 131072
  float* obuf  = ws + 18180096;      // 1048576
  float* xb    = ws + 19228672;      // 1048576
  float* hb    = ws + 20277248;      // 1048576
  float* comb  = ws + 21325824;      // 1048576

  // 1. xn (plain normalize) + routing + lb
  ln_kernel<<<2048,256,0,stream>>>(x, xn, nullptr, nullptr);
  routing_kernel<<<2048,256,0,stream>>>(xn, gr_g, gr_b, q6_w, logtemp,
                                        grp_g, grp_b, gpw, gpb, gw, coef, part);
  lb_kernel<<<1,64,0,stream>>>(part, out + 1048576);

  // 2. MoE experts -> group_outs (go)
  for(int e=0;e<6;e++){
    gemm64<0,0><<<dim3(4,128),256,0,stream>>>(xn, me_val + (size_t)e*DFF*DD, vbuf,
        NTOK,DFF,DD, me_g+e*DD, me_b+e*DD, nullptr,nullptr,nullptr,nullptr);
    gemm64<1,0><<<dim3(4,128),256,0,stream>>>(xn, me_gate + (size_t)e*DFF*DD, gvb,
        NTOK,DFF,DD, me_g+e*DD, me_b+e*DD, vbuf,nullptr,nullptr,nullptr);
    float* gout = go + (size_t)(e>>1)*NTOK*DD;
    if(e&1)
      gemm64<2,1><<<dim3(2,128),256,0,stream>>>(gvb, me_out + (size_t)e*DD*DFF, gout,
          NTOK,DD,DFF, nullptr,nullptr,nullptr, coef+(size_t)e*NTOK, nullptr,nullptr);
    else
      gemm64<2,0><<<dim3(2,128),256,0,stream>>>(gvb, me_out + (size_t)e*DD*DFF, gout,
          NTOK,DD,DFF, nullptr,nullptr,nullptr, coef+(size_t)e*NTOK, nullptr,nullptr);
  }

  // 3. combined = go0+go1+go2
  add3_kernel<<<4096,256,0,stream>>>(go, go+(size_t)NTOK*DD, go+(size_t)2*NTOK*DD, comb, NTOK*DD);

  // 4. bridges
  const int pairs[3][2] = {{0,1},{1,2},{0,2}};
  for(int i=0;i<3;i++){
    const float* xq = go + (size_t)pairs[i][0]*NTOK*DD;
    const float* xk = go + (size_t)pairs[i][1]*NTOK*DD;
    ln_kernel<<<2048,256,0,stream>>>(xq, qn,  nq_g+i*DD,  nq_b+i*DD);
    ln_kernel<<<2048,256,0,stream>>>(xk, kvn, nkv_g+i*DD, nkv_b+i*DD);
    gemm64<0,0><<<dim3(2,128),256,0,stream>>>(qn,  br_in + (size_t)i*3*DD*DD, Qb,
        NTOK,DD,DD, nullptr,nullptr,nullptr,nullptr,nullptr,nullptr);
    gemm64<0,0><<<dim3(4,128),256,0,stream>>>(kvn, br_in + (size_t)i*3*DD*DD + DD*DD, KVb,
        NTOK,2*DD,DD, nullptr,nullptr,nullptr,nullptr,nullptr,nullptr);
    attn_partial<<<dim3(32,NHH,KSPLIT),256,0,stream>>>(Qb, KVb, opart, mpart, lpart);
    attn_merge<<<128,256,0,stream>>>(opart, mpart, lpart, obuf);
    gemm64<3,0><<<dim3(2,128),256,0,stream>>>(obuf, br_outw + (size_t)i*DD*DD, xb,
        NTOK,DD,DD, nullptr,nullptr,nullptr,nullptr, xq, nullptr);
    ln_kernel<<<2048,256,0,stream>>>(xb, hb, nff_g+i*DD, nff_b+i*DD);
    gemm64<0,0><<<dim3(4,128),256,0,stream>>>(hb, brv_w + (size_t)i*2*DD*DD, vbuf,
        NTOK,2*DD,DD, nullptr,nullptr,nullptr,nullptr,nullptr,nullptr);
    gemm64<1,0><<<dim3(4,128),256,0,stream>>>(hb, brg_w + (size_t)i*2*DD*DD, gvb,
        NTOK,2*DD,DD, nullptr,nullptr, vbuf,nullptr,nullptr,nullptr);
    gemm64<4,0><<<dim3(2,128),256,0,stream>>>(gvb, brf_w + (size_t)i*DD*2*DD, comb,
        NTOK,DD,2*DD, nullptr,nullptr,nullptr,nullptr, xb, br_gate+i);
  }

  // 5. final LN + projection
  ln_kernel<<<2048,256,0,stream>>>(comb, hb, on_g, on_b);
  gemm64<0,0><<<dim3(2,128),256,0,stream>>>(hb, out_w, out,
      NTOK,DD,DD, nullptr,nullptr,nullptr,nullptr,nullptr,nullptr);
}

// Round 3
// 679.545 us; speedup vs baseline: 1.7335x; 1.3683x over previous
//
#include <hip/hip_runtime.h>
#include <math.h>

#define DD    128
#define DFF   256
#define NHH   4
#define HDD   32
#define BB    8
#define TT    1024
#define NTOK  (BB*TT)          // 8192
#define KSPLIT 4
#define KCH   (TT/KSPLIT)      // 256
#define AKEYS 64               // keys per LDS tile
#define LDK   72               // padded LDS row stride (bf16 elements), 144B

typedef __bf16 bf16x8 __attribute__((ext_vector_type(8)));
typedef float  f32x4  __attribute__((ext_vector_type(4)));

// ---------------- wave helpers (wave64) ----------------
__device__ __forceinline__ float wsum(float v){
#pragma unroll
  for(int o=32;o>0;o>>=1) v += __shfl_xor(v,o,64);
  return v;
}
__device__ __forceinline__ float wmaxr(float v){
#pragma unroll
  for(int o=32;o>0;o>>=1) v = fmaxf(v,__shfl_xor(v,o,64));
  return v;
}
__device__ __forceinline__ unsigned short f2bf(float x){
  unsigned int u = __float_as_uint(x);
  u += 0x7fffu + ((u>>16)&1u);
  return (unsigned short)(u>>16);
}

// stage 16 consecutive floats -> 16 bf16 in LDS (two 16B writes)
__device__ __forceinline__ void stage16(const float* __restrict__ gp,
                                        const float* __restrict__ sv,
                                        const float* __restrict__ bvp,
                                        unsigned short* __restrict__ dst){
  float4 f0 = *reinterpret_cast<const float4*>(gp);
  float4 f1 = *reinterpret_cast<const float4*>(gp+4);
  float4 f2 = *reinterpret_cast<const float4*>(gp+8);
  float4 f3 = *reinterpret_cast<const float4*>(gp+12);
  float f[16] = {f0.x,f0.y,f0.z,f0.w, f1.x,f1.y,f1.z,f1.w,
                 f2.x,f2.y,f2.z,f2.w, f3.x,f3.y,f3.z,f3.w};
  if(sv){
#pragma unroll
    for(int j=0;j<16;j++) f[j] = f[j]*sv[j] + bvp[j];
  }
  unsigned short h[16];
#pragma unroll
  for(int j=0;j<16;j++) h[j] = f2bf(f[j]);
  *reinterpret_cast<uint4*>(dst)   = *reinterpret_cast<const uint4*>(h);
  *reinterpret_cast<uint4*>(dst+8) = *reinterpret_cast<const uint4*>(h+8);
}

// ---------------- LayerNorm: one wave per token ----------------
__global__ __launch_bounds__(256) void ln_kernel(const float* __restrict__ in,
                                                 float* __restrict__ out,
                                                 const float* __restrict__ g,
                                                 const float* __restrict__ b){
  int lane = threadIdx.x & 63;
  int t = (blockIdx.x<<2) + (threadIdx.x>>6);
  const float* row = in + (size_t)t*DD;
  float x0 = row[lane], x1 = row[lane+64];
  float m = wsum(x0+x1) * (1.0f/DD);
  float d0 = x0-m, d1 = x1-m;
  float v = wsum(d0*d0 + d1*d1) * (1.0f/DD);
  float r = rsqrtf(v + 1e-5f);
  float y0 = d0*r, y1 = d1*r;
  if(g){ y0 = y0*g[lane] + b[lane]; y1 = y1*g[lane+64] + b[lane+64]; }
  out[(size_t)t*DD+lane]    = y0;
  out[(size_t)t*DD+lane+64] = y1;
}

// ---------------- routing: one wave per token ----------------
__global__ __launch_bounds__(256) void routing_kernel(
    const float* __restrict__ xn,
    const float* __restrict__ gr_g, const float* __restrict__ gr_b,
    const float* __restrict__ q6,   const float* __restrict__ logtemp,
    const float* __restrict__ grp_g,const float* __restrict__ grp_b,
    const float* __restrict__ gpw,  const float* __restrict__ gpb,
    float* __restrict__ gw_out, float* __restrict__ coef, float* __restrict__ part){
  __shared__ float sp[4][9];
  int lane = threadIdx.x & 63;
  int wv   = threadIdx.x >> 6;
  int t    = (blockIdx.x<<2) + wv;
  const float* xr = xn + (size_t)t*DD;
  float x0 = xr[lane], x1 = xr[lane+64];
  float h0 = x0*gr_g[lane]+gr_b[lane];
  float h1 = x1*gr_g[lane+64]+gr_b[lane+64];
  float sb[6];
#pragma unroll
  for(int j=0;j<6;j++){
    float p = h0*q6[j*DD+lane] + h1*q6[j*DD+lane+64];
    sb[j] = tanhf(wsum(p));
  }
  float sim = 0.f;
#pragma unroll
  for(int j=0;j<6;j++) sim += ((lane>>(5-j))&1) ? sb[j] : -sb[j];
  float temp = expf(logtemp[0]); temp = fminf(fmaxf(temp,0.1f),5.0f);
  float mx = wmaxr(sim);
  float p  = expf((sim-mx)/temp);
  float w  = p / wsum(p);
  float sh[6];
#pragma unroll
  for(int j=0;j<6;j++) sh[j] = wsum(((lane>>(5-j))&1) ? w : -w);
  const float A0[6]={0,1,1,0,1,1}, A1[6]={0,-1,0,1,0,0}, A2[6]={-1,0,-1,-1,0,-1};
  float l0=0,l1=0,l2=0;
#pragma unroll
  for(int j=0;j<6;j++){ l0+=sh[j]*A0[j]; l1+=sh[j]*A1[j]; l2+=sh[j]*A2[j]; }
  float m3 = fmaxf(l0,fmaxf(l1,l2));
  float e0=expf(l0-m3), e1=expf(l1-m3), e2=expf(l2-m3);
  float inv3 = 1.0f/(e0+e1+e2);
  float g0=e0*inv3, g1=e1*inv3, g2=e2*inv3;
  if(lane==0){ gw_out[t*3]=g0; gw_out[t*3+1]=g1; gw_out[t*3+2]=g2; }
  float gwv[3]={g0,g1,g2};
  float pw[6];
#pragma unroll
  for(int g=0; g<3; g++){
    float hg0 = x0*grp_g[g*DD+lane]    + grp_b[g*DD+lane];
    float hg1 = x1*grp_g[g*DD+lane+64] + grp_b[g*DD+lane+64];
    float q0 = wsum(hg0*gpw[(g*2+0)*DD+lane] + hg1*gpw[(g*2+0)*DD+lane+64]) + gpb[g*2+0];
    float q1 = wsum(hg0*gpw[(g*2+1)*DD+lane] + hg1*gpw[(g*2+1)*DD+lane+64]) + gpb[g*2+1];
    float mm = fmaxf(q0,q1);
    float a0 = expf(q0-mm), a1 = expf(q1-mm);
    float inv = 1.0f/(a0+a1);
    float w0 = a0*inv, w1 = a1*inv;
    pw[g*2]=w0; pw[g*2+1]=w1;
    float invs = 1.0f/(w0+w1+1e-8f);
    if(lane==0){
      coef[(size_t)(2*g  )*NTOK + t] = gwv[g]*w0*invs;
      coef[(size_t)(2*g+1)*NTOK + t] = gwv[g]*w1*invs;
    }
  }
  if(lane==0){
    sp[wv][0]=g0; sp[wv][1]=g1; sp[wv][2]=g2;
#pragma unroll
    for(int k=0;k<6;k++) sp[wv][3+k]=pw[k];
  }
  __syncthreads();
  if(threadIdx.x<9){
    part[blockIdx.x*9+threadIdx.x] =
      sp[0][threadIdx.x]+sp[1][threadIdx.x]+sp[2][threadIdx.x]+sp[3][threadIdx.x];
  }
}

// ---------------- load-balance loss reduce (deterministic) ----------------
__global__ void lb_kernel(const float* __restrict__ part, float* __restrict__ outlb){
  __shared__ float sums[9];
  int c = threadIdx.x;
  if(c<9){
    float s=0;
    for(int i=0;i<2048;i++) s += part[i*9+c];
    sums[c]=s;
  }
  __syncthreads();
  if(threadIdx.x==0){
    const float invN = 1.0f/(float)NTOK;
    float lb=0;
    for(int k=0;k<9;k++){ float mw = sums[k]*invN; lb -= mw*logf(mw+1e-8f); }
    outlb[0] = lb*0.01f;
  }
}

// ---------------- bf16 MFMA GEMM: C[M,N] = epi(A[M,K] @ W[N,K]^T) ----------------
// 64x64 tile, 4 waves (2x2), each wave 32x32 via 2x2 16x16x32 frags.
// MODE 0: store  2: rowv[m]*acc (+C if ADD)  3: resid+acc  4: C += BW*sigmoid(*gptr)*(resid+acc)
template<int MODE, int ADD>
__global__ __launch_bounds__(256) void gemm_mfma(
    const float* __restrict__ A, const float* __restrict__ W, float* __restrict__ C,
    int M, int N, int K,
    const float* __restrict__ sv, const float* __restrict__ bv,
    const float* __restrict__ rowv,
    const float* __restrict__ resid, const float* __restrict__ gptr){
  __shared__ unsigned short As[64*LDK];
  __shared__ unsigned short Ws[64*LDK];
  int tid  = threadIdx.x;
  int m0   = blockIdx.y*64, n0 = blockIdx.x*64;
  int w    = tid>>6, lane = tid&63;
  int wr   = (w>>1)*32, wc = (w&1)*32;
  int r    = tid>>2, seg = (tid&3)*16;
  f32x4 acc[2][2] = {};
  for(int k0=0;k0<K;k0+=64){
    __syncthreads();
    stage16(A + (size_t)(m0+r)*K + k0 + seg,
            sv ? sv+k0+seg : nullptr, sv ? bv+k0+seg : nullptr,
            &As[r*LDK + seg]);
    stage16(W + (size_t)(n0+r)*K + k0 + seg, nullptr, nullptr,
            &Ws[r*LDK + seg]);
    __syncthreads();
#pragma unroll
    for(int kk=0;kk<64;kk+=32){
      int ko = kk + (lane>>4)*8;
      bf16x8 a0 = *reinterpret_cast<const bf16x8*>(&As[(wr    + (lane&15))*LDK + ko]);
      bf16x8 a1 = *reinterpret_cast<const bf16x8*>(&As[(wr+16 + (lane&15))*LDK + ko]);
      bf16x8 b0 = *reinterpret_cast<const bf16x8*>(&Ws[(wc    + (lane&15))*LDK + ko]);
      bf16x8 b1 = *reinterpret_cast<const bf16x8*>(&Ws[(wc+16 + (lane&15))*LDK + ko]);
      acc[0][0] = __builtin_amdgcn_mfma_f32_16x16x32_bf16(a0,b0,acc[0][0],0,0,0);
      acc[0][1] = __builtin_amdgcn_mfma_f32_16x16x32_bf16(a0,b1,acc[0][1],0,0,0);
      acc[1][0] = __builtin_amdgcn_mfma_f32_16x16x32_bf16(a1,b0,acc[1][0],0,0,0);
      acc[1][1] = __builtin_amdgcn_mfma_f32_16x16x32_bf16(a1,b1,acc[1][1],0,0,0);
    }
  }
#pragma unroll
  for(int i=0;i<2;i++){
#pragma unroll
    for(int j=0;j<2;j++){
      int mb = m0 + wr + i*16 + (lane>>4)*4;
      int n  = n0 + wc + j*16 + (lane&15);
#pragma unroll
      for(int rg=0;rg<4;rg++){
        int m = mb + rg;
        float v = acc[i][j][rg];
        size_t o = (size_t)m*N + n;
        if(MODE==0){ C[o] = v; }
        else if(MODE==2){ float rr = rowv[m]*v; C[o] = ADD ? (C[o]+rr) : rr; }
        else if(MODE==3){ C[o] = resid[o] + v; }
        else if(MODE==4){
          float gs = (0.5f/3.0f)/(1.0f+expf(-gptr[0]));
          C[o] += gs*(resid[o]+v);
        }
      }
    }
  }
}

// ---------------- dual-W bf16 MFMA GEMM: C = silu(A@G^T) * (A@V^T) ----------------
__global__ __launch_bounds__(256) void gemm_dual(
    const float* __restrict__ A, const float* __restrict__ G, const float* __restrict__ V,
    float* __restrict__ C, int M, int N, int K,
    const float* __restrict__ sv, const float* __restrict__ bv){
  __shared__ unsigned short As[64*LDK];
  __shared__ unsigned short Gs[64*LDK];
  __shared__ unsigned short Vs[64*LDK];
  int tid  = threadIdx.x;
  int m0   = blockIdx.y*64, n0 = blockIdx.x*64;
  int w    = tid>>6, lane = tid&63;
  int wr   = (w>>1)*32, wc = (w&1)*32;
  int r    = tid>>2, seg = (tid&3)*16;
  f32x4 accg[2][2] = {};
  f32x4 accv[2][2] = {};
  for(int k0=0;k0<K;k0+=64){
    __syncthreads();
    stage16(A + (size_t)(m0+r)*K + k0 + seg,
            sv ? sv+k0+seg : nullptr, sv ? bv+k0+seg : nullptr,
            &As[r*LDK + seg]);
    stage16(G + (size_t)(n0+r)*K + k0 + seg, nullptr, nullptr, &Gs[r*LDK + seg]);
    stage16(V + (size_t)(n0+r)*K + k0 + seg, nullptr, nullptr, &Vs[r*LDK + seg]);
    __syncthreads();
#pragma unroll
    for(int kk=0;kk<64;kk+=32){
      int ko = kk + (lane>>4)*8;
      bf16x8 a0 = *reinterpret_cast<const bf16x8*>(&As[(wr    + (lane&15))*LDK + ko]);
      bf16x8 a1 = *reinterpret_cast<const bf16x8*>(&As[(wr+16 + (lane&15))*LDK + ko]);
      bf16x8 g0 = *reinterpret_cast<const bf16x8*>(&Gs[(wc    + (lane&15))*LDK + ko]);
      bf16x8 g1 = *reinterpret_cast<const bf16x8*>(&Gs[(wc+16 + (lane&15))*LDK + ko]);
      bf16x8 v0 = *reinterpret_cast<const bf16x8*>(&Vs[(wc    + (lane&15))*LDK + ko]);
      bf16x8 v1 = *reinterpret_cast<const bf16x8*>(&Vs[(wc+16 + (lane&15))*LDK + ko]);
      accg[0][0] = __builtin_amdgcn_mfma_f32_16x16x32_bf16(a0,g0,accg[0][0],0,0,0);
      accg[0][1] = __builtin_amdgcn_mfma_f32_16x16x32_bf16(a0,g1,accg[0][1],0,0,0);
      accg[1][0] = __builtin_amdgcn_mfma_f32_16x16x32_bf16(a1,g0,accg[1][0],0,0,0);
      accg[1][1] = __builtin_amdgcn_mfma_f32_16x16x32_bf16(a1,g1,accg[1][1],0,0,0);
      accv[0][0] = __builtin_amdgcn_mfma_f32_16x16x32_bf16(a0,v0,accv[0][0],0,0,0);
      accv[0][1] = __builtin_amdgcn_mfma_f32_16x16x32_bf16(a0,v1,accv[0][1],0,0,0);
      accv[1][0] = __builtin_amdgcn_mfma_f32_16x16x32_bf16(a1,v0,accv[1][0],0,0,0);
      accv[1][1] = __builtin_amdgcn_mfma_f32_16x16x32_bf16(a1,v1,accv[1][1],0,0,0);
    }
  }
#pragma unroll
  for(int i=0;i<2;i++){
#pragma unroll
    for(int j=0;j<2;j++){
      int mb = m0 + wr + i*16 + (lane>>4)*4;
      int n  = n0 + wc + j*16 + (lane&15);
#pragma unroll
      for(int rg=0;rg<4;rg++){
        float gg = accg[i][j][rg];
        float vv = accv[i][j][rg];
        float sg = gg/(1.0f+expf(-gg));
        C[(size_t)(mb+rg)*N + n] = sg*vv;
      }
    }
  }
}

// ---------------- attention partial: LDS-staged K/V, online softmax ----------------
__global__ __launch_bounds__(256) void attn_partial(
    const float* __restrict__ Qb, const float* __restrict__ KVb,
    float* __restrict__ opart, float* __restrict__ mpart, float* __restrict__ lpart){
  __shared__ float Ks[AKEYS][HDD];   // 8 KB
  __shared__ float Vs[AKEYS][HDD];   // 8 KB
  int tid = threadIdx.x;
  int row = blockIdx.x*256 + tid;
  int b   = blockIdx.x >> 2;
  int h   = blockIdx.y;
  int sp  = blockIdx.z;
  const float scale = 0.17677669529663687f;   // 1/sqrt(32)
  float q[HDD];
  const float* qrow = Qb + (size_t)row*DD + h*HDD;
#pragma unroll
  for(int d=0;d<HDD;d++) q[d] = qrow[d]*scale;
  float M = -1e30f, l = 0.f;
  float o[HDD];
#pragma unroll
  for(int d=0;d<HDD;d++) o[d]=0.f;
  const float* KVbase = KVb + ((size_t)(b*TT + sp*KCH))*(2*DD) + h*HDD;

  for(int t0=0; t0<KCH; t0+=AKEYS){
    __syncthreads();
#pragma unroll
    for(int l4=0; l4<4; l4++){
      int idx  = tid + l4*256;
      int key  = idx >> 4;
      int part = idx & 15;
      const float4 v = *reinterpret_cast<const float4*>(
          KVbase + (size_t)(t0+key)*(2*DD) + (part<8 ? part*4 : DD + (part-8)*4));
      if(part<8) *reinterpret_cast<float4*>(&Ks[key][part*4])     = v;
      else       *reinterpret_cast<float4*>(&Vs[key][(part-8)*4]) = v;
    }
    __syncthreads();
#pragma unroll 2
    for(int kk=0; kk<AKEYS; kk++){
      float s = 0.f;
#pragma unroll
      for(int d=0;d<HDD;d++) s += q[d]*Ks[kk][d];
      if(__any(s > M + 8.0f)){
        float mn = fmaxf(M, s);
        float sc = expf(M - mn);
        l *= sc;
#pragma unroll
        for(int d=0;d<HDD;d++) o[d] *= sc;
        M = mn;
      }
      float p = expf(s - M);
      l += p;
#pragma unroll
      for(int d=0;d<HDD;d++) o[d] += p*Vs[kk][d];
    }
  }
  float* op = opart + ((size_t)sp*NTOK + row)*DD + h*HDD;
#pragma unroll
  for(int d=0;d<HDD;d++) op[d] = o[d];
  mpart[((size_t)sp*NTOK+row)*NHH + h] = M;
  lpart[((size_t)sp*NTOK+row)*NHH + h] = l;
}

__global__ __launch_bounds__(256) void attn_merge(
    const float* __restrict__ opart, const float* __restrict__ mpart,
    const float* __restrict__ lpart, float* __restrict__ O){
  int idx = blockIdx.x*256 + threadIdx.x;  // row*NH + h
  if(idx >= NTOK*NHH) return;
  int row = idx >> 2, h = idx & 3;
  float mv[KSPLIT], lv[KSPLIT];
  float M = -1e30f;
#pragma unroll
  for(int s=0;s<KSPLIT;s++){
    mv[s] = mpart[((size_t)s*NTOK+row)*NHH + h];
    lv[s] = lpart[((size_t)s*NTOK+row)*NHH + h];
    M = fmaxf(M, mv[s]);
  }
  float f[KSPLIT]; float l=0;
#pragma unroll
  for(int s=0;s<KSPLIT;s++){ f[s] = expf(mv[s]-M); l += lv[s]*f[s]; }
  float invl = 1.0f/l;
  float* orow = O + (size_t)row*DD + h*HDD;
#pragma unroll
  for(int d=0;d<HDD;d++){
    float acc=0;
#pragma unroll
    for(int s=0;s<KSPLIT;s++) acc += opart[((size_t)s*NTOK+row)*DD + h*HDD + d]*f[s];
    orow[d] = acc*invl;
  }
}

__global__ __launch_bounds__(256) void add3_kernel(const float* __restrict__ a,
                                                   const float* __restrict__ b,
                                                   const float* __restrict__ c,
                                                   float* __restrict__ out, int n){
  int i = blockIdx.x*256 + threadIdx.x;
  if(i<n) out[i] = a[i]+b[i]+c[i];
}

// ---------------- launch ----------------
extern "C" void kernel_launch(void* const* d_in, const int* in_sizes, int n_in,
                              void* d_out, int out_size, void* d_ws, size_t ws_size,
                              hipStream_t stream){
  (void)in_sizes; (void)n_in; (void)out_size; (void)ws_size;
  const float* x       = (const float*)d_in[0];
  const float* gr_g    = (const float*)d_in[1];
  const float* gr_b    = (const float*)d_in[2];
  const float* q6_w    = (const float*)d_in[3];
  const float* logtemp = (const float*)d_in[4];
  const float* grp_g   = (const float*)d_in[5];
  const float* grp_b   = (const float*)d_in[6];
  const float* gpw     = (const float*)d_in[7];
  const float* gpb     = (const float*)d_in[8];
  const float* me_g    = (const float*)d_in[9];
  const float* me_b    = (const float*)d_in[10];
  const float* me_gate = (const float*)d_in[11];
  const float* me_val  = (const float*)d_in[12];
  const float* me_out  = (const float*)d_in[13];
  const float* br_in   = (const float*)d_in[14];
  const float* br_outw = (const float*)d_in[15];
  const float* nq_g    = (const float*)d_in[16];
  const float* nq_b    = (const float*)d_in[17];
  const float* nkv_g   = (const float*)d_in[18];
  const float* nkv_b   = (const float*)d_in[19];
  const float* nff_g   = (const float*)d_in[20];
  const float* nff_b   = (const float*)d_in[21];
  const float* brg_w   = (const float*)d_in[22];
  const float* brv_w   = (const float*)d_in[23];
  const float* brf_w   = (const float*)d_in[24];
  const float* br_gate = (const float*)d_in[25];
  const float* on_g    = (const float*)d_in[26];
  const float* on_b    = (const float*)d_in[27];
  const float* out_w   = (const float*)d_in[28];
  float* out = (float*)d_out;
  float* ws  = (float*)d_ws;

  float* xn    = ws;                 // 1048576
  float* gw    = ws + 1048576;       // 24576
  float* coef  = ws + 1073152;       // 49152
  float* part  = ws + 1122304;       // 18432
  float* gvb   = ws + 3237888;       // 2097152
  float* go    = ws + 5335040;       // 3*1048576
  float* qn    = ws + 8480768;       // 1048576
  float* kvn   = ws + 9529344;       // 1048576
  float* Qb    = ws + 10577920;      // 1048576
  float* KVb   = ws + 11626496;      // 2097152
  float* opart = ws + 13723648;      // 4194304
  float* mpart = ws + 17917952;      // 131072
  float* lpart = ws + 18049024;      // 131072
  float* obuf  = ws + 18180096;      // 1048576
  float* xb    = ws + 19228672;      // 1048576
  float* hb    = ws + 20277248;      // 1048576
  float* comb  = ws + 21325824;      // 1048576

  // 1. xn (plain normalize) + routing + lb
  ln_kernel<<<2048,256,0,stream>>>(x, xn, nullptr, nullptr);
  routing_kernel<<<2048,256,0,stream>>>(xn, gr_g, gr_b, q6_w, logtemp,
                                        grp_g, grp_b, gpw, gpb, gw, coef, part);
  lb_kernel<<<1,64,0,stream>>>(part, out + 1048576);

  // 2. MoE experts -> group_outs (go)
  for(int e=0;e<6;e++){
    gemm_dual<<<dim3(4,128),256,0,stream>>>(xn,
        me_gate + (size_t)e*DFF*DD, me_val + (size_t)e*DFF*DD, gvb,
        NTOK,DFF,DD, me_g+e*DD, me_b+e*DD);
    float* gout = go + (size_t)(e>>1)*NTOK*DD;
    if(e&1)
      gemm_mfma<2,1><<<dim3(2,128),256,0,stream>>>(gvb, me_out + (size_t)e*DD*DFF, gout,
          NTOK,DD,DFF, nullptr,nullptr, coef+(size_t)e*NTOK, nullptr,nullptr);
    else
      gemm_mfma<2,0><<<dim3(2,128),256,0,stream>>>(gvb, me_out + (size_t)e*DD*DFF, gout,
          NTOK,DD,DFF, nullptr,nullptr, coef+(size_t)e*NTOK, nullptr,nullptr);
  }

  // 3. combined = go0+go1+go2
  add3_kernel<<<4096,256,0,stream>>>(go, go+(size_t)NTOK*DD, go+(size_t)2*NTOK*DD, comb, NTOK*DD);

  // 4. bridges
  const int pairs[3][2] = {{0,1},{1,2},{0,2}};
  for(int i=0;i<3;i++){
    const float* xq = go + (size_t)pairs[i][0]*NTOK*DD;
    const float* xk = go + (size_t)pairs[i][1]*NTOK*DD;
    ln_kernel<<<2048,256,0,stream>>>(xq, qn,  nq_g+i*DD,  nq_b+i*DD);
    ln_kernel<<<2048,256,0,stream>>>(xk, kvn, nkv_g+i*DD, nkv_b+i*DD);
    gemm_mfma<0,0><<<dim3(2,128),256,0,stream>>>(qn,  br_in + (size_t)i*3*DD*DD, Qb,
        NTOK,DD,DD, nullptr,nullptr,nullptr,nullptr,nullptr);
    gemm_mfma<0,0><<<dim3(4,128),256,0,stream>>>(kvn, br_in + (size_t)i*3*DD*DD + DD*DD, KVb,
        NTOK,2*DD,DD, nullptr,nullptr,nullptr,nullptr,nullptr);
    attn_partial<<<dim3(32,NHH,KSPLIT),256,0,stream>>>(Qb, KVb, opart, mpart, lpart);
    attn_merge<<<128,256,0,stream>>>(opart, mpart, lpart, obuf);
    gemm_mfma<3,0><<<dim3(2,128),256,0,stream>>>(obuf, br_outw + (size_t)i*DD*DD, xb,
        NTOK,DD,DD, nullptr,nullptr,nullptr, xq, nullptr);
    ln_kernel<<<2048,256,0,stream>>>(xb, hb, nff_g+i*DD, nff_b+i*DD);
    gemm_dual<<<dim3(4,128),256,0,stream>>>(hb,
        brg_w + (size_t)i*2*DD*DD, brv_w + (size_t)i*2*DD*DD, gvb,
        NTOK,2*DD,DD, nullptr,nullptr);
    gemm_mfma<4,0><<<dim3(2,128),256,0,stream>>>(gvb, brf_w + (size_t)i*DD*2*DD, comb,
        NTOK,DD,2*DD, nullptr,nullptr,nullptr, xb, br_gate+i);
  }

  // 5. final LN + projection
  ln_kernel<<<2048,256,0,stream>>>(comb, hb, on_g, on_b);
  gemm_mfma<0,0><<<dim3(2,128),256,0,stream>>>(hb, out_w, out,
      NTOK,DD,DD, nullptr,nullptr,nullptr,nullptr,nullptr);
}

// Round 4
// 413.720 us; speedup vs baseline: 2.8473x; 1.6425x over previous
//
#include <hip/hip_runtime.h>
#include <math.h>

#define DD    128
#define DFF   256
#define NHH   4
#define HDD   32
#define BB    8
#define TT    1024
#define NTOK  (BB*TT)          // 8192
#define LDK   72               // padded LDS row stride (bf16 elements) for GEMM tiles

typedef __bf16 bf16x8 __attribute__((ext_vector_type(8)));
typedef float  f32x4  __attribute__((ext_vector_type(4)));

// ---------------- wave helpers (wave64) ----------------
__device__ __forceinline__ float wsum(float v){
#pragma unroll
  for(int o=32;o>0;o>>=1) v += __shfl_xor(v,o,64);
  return v;
}
__device__ __forceinline__ float wmaxr(float v){
#pragma unroll
  for(int o=32;o>0;o>>=1) v = fmaxf(v,__shfl_xor(v,o,64));
  return v;
}
__device__ __forceinline__ unsigned short f2bf(float x){
  unsigned int u = __float_as_uint(x);
  u += 0x7fffu + ((u>>16)&1u);
  return (unsigned short)(u>>16);
}

// stage 16 consecutive floats -> 16 bf16 in LDS (two 16B writes)
__device__ __forceinline__ void stage16(const float* __restrict__ gp,
                                        const float* __restrict__ sv,
                                        const float* __restrict__ bvp,
                                        unsigned short* __restrict__ dst){
  float4 f0 = *reinterpret_cast<const float4*>(gp);
  float4 f1 = *reinterpret_cast<const float4*>(gp+4);
  float4 f2 = *reinterpret_cast<const float4*>(gp+8);
  float4 f3 = *reinterpret_cast<const float4*>(gp+12);
  float f[16] = {f0.x,f0.y,f0.z,f0.w, f1.x,f1.y,f1.z,f1.w,
                 f2.x,f2.y,f2.z,f2.w, f3.x,f3.y,f3.z,f3.w};
  if(sv){
#pragma unroll
    for(int j=0;j<16;j++) f[j] = f[j]*sv[j] + bvp[j];
  }
  unsigned short h[16];
#pragma unroll
  for(int j=0;j<16;j++) h[j] = f2bf(f[j]);
  *reinterpret_cast<uint4*>(dst)   = *reinterpret_cast<const uint4*>(h);
  *reinterpret_cast<uint4*>(dst+8) = *reinterpret_cast<const uint4*>(h+8);
}

// ---------------- LayerNorm: one wave per token ----------------
__global__ __launch_bounds__(256) void ln_kernel(const float* __restrict__ in,
                                                 float* __restrict__ out,
                                                 const float* __restrict__ g,
                                                 const float* __restrict__ b){
  int lane = threadIdx.x & 63;
  int t = (blockIdx.x<<2) + (threadIdx.x>>6);
  const float* row = in + (size_t)t*DD;
  float x0 = row[lane], x1 = row[lane+64];
  float m = wsum(x0+x1) * (1.0f/DD);
  float d0 = x0-m, d1 = x1-m;
  float v = wsum(d0*d0 + d1*d1) * (1.0f/DD);
  float r = rsqrtf(v + 1e-5f);
  float y0 = d0*r, y1 = d1*r;
  if(g){ y0 = y0*g[lane] + b[lane]; y1 = y1*g[lane+64] + b[lane+64]; }
  out[(size_t)t*DD+lane]    = y0;
  out[(size_t)t*DD+lane+64] = y1;
}

// ---------------- routing: one wave per token ----------------
__global__ __launch_bounds__(256) void routing_kernel(
    const float* __restrict__ xn,
    const float* __restrict__ gr_g, const float* __restrict__ gr_b,
    const float* __restrict__ q6,   const float* __restrict__ logtemp,
    const float* __restrict__ grp_g,const float* __restrict__ grp_b,
    const float* __restrict__ gpw,  const float* __restrict__ gpb,
    float* __restrict__ gw_out, float* __restrict__ coef, float* __restrict__ part){
  __shared__ float sp[4][9];
  int lane = threadIdx.x & 63;
  int wv   = threadIdx.x >> 6;
  int t    = (blockIdx.x<<2) + wv;
  const float* xr = xn + (size_t)t*DD;
  float x0 = xr[lane], x1 = xr[lane+64];
  float h0 = x0*gr_g[lane]+gr_b[lane];
  float h1 = x1*gr_g[lane+64]+gr_b[lane+64];
  float sb[6];
#pragma unroll
  for(int j=0;j<6;j++){
    float p = h0*q6[j*DD+lane] + h1*q6[j*DD+lane+64];
    sb[j] = tanhf(wsum(p));
  }
  float sim = 0.f;
#pragma unroll
  for(int j=0;j<6;j++) sim += ((lane>>(5-j))&1) ? sb[j] : -sb[j];
  float temp = expf(logtemp[0]); temp = fminf(fmaxf(temp,0.1f),5.0f);
  float mx = wmaxr(sim);
  float p  = expf((sim-mx)/temp);
  float w  = p / wsum(p);
  float sh[6];
#pragma unroll
  for(int j=0;j<6;j++) sh[j] = wsum(((lane>>(5-j))&1) ? w : -w);
  const float A0[6]={0,1,1,0,1,1}, A1[6]={0,-1,0,1,0,0}, A2[6]={-1,0,-1,-1,0,-1};
  float l0=0,l1=0,l2=0;
#pragma unroll
  for(int j=0;j<6;j++){ l0+=sh[j]*A0[j]; l1+=sh[j]*A1[j]; l2+=sh[j]*A2[j]; }
  float m3 = fmaxf(l0,fmaxf(l1,l2));
  float e0=expf(l0-m3), e1=expf(l1-m3), e2=expf(l2-m3);
  float inv3 = 1.0f/(e0+e1+e2);
  float g0=e0*inv3, g1=e1*inv3, g2=e2*inv3;
  if(lane==0){ gw_out[t*3]=g0; gw_out[t*3+1]=g1; gw_out[t*3+2]=g2; }
  float gwv[3]={g0,g1,g2};
  float pw[6];
#pragma unroll
  for(int g=0; g<3; g++){
    float hg0 = x0*grp_g[g*DD+lane]    + grp_b[g*DD+lane];
    float hg1 = x1*grp_g[g*DD+lane+64] + grp_b[g*DD+lane+64];
    float q0 = wsum(hg0*gpw[(g*2+0)*DD+lane] + hg1*gpw[(g*2+0)*DD+lane+64]) + gpb[g*2+0];
    float q1 = wsum(hg0*gpw[(g*2+1)*DD+lane] + hg1*gpw[(g*2+1)*DD+lane+64]) + gpb[g*2+1];
    float mm = fmaxf(q0,q1);
    float a0 = expf(q0-mm), a1 = expf(q1-mm);
    float inv = 1.0f/(a0+a1);
    float w0 = a0*inv, w1 = a1*inv;
    pw[g*2]=w0; pw[g*2+1]=w1;
    float invs = 1.0f/(w0+w1+1e-8f);
    if(lane==0){
      coef[(size_t)(2*g  )*NTOK + t] = gwv[g]*w0*invs;
      coef[(size_t)(2*g+1)*NTOK + t] = gwv[g]*w1*invs;
    }
  }
  if(lane==0){
    sp[wv][0]=g0; sp[wv][1]=g1; sp[wv][2]=g2;
#pragma unroll
    for(int k=0;k<6;k++) sp[wv][3+k]=pw[k];
  }
  __syncthreads();
  if(threadIdx.x<9){
    part[blockIdx.x*9+threadIdx.x] =
      sp[0][threadIdx.x]+sp[1][threadIdx.x]+sp[2][threadIdx.x]+sp[3][threadIdx.x];
  }
}

// ---------------- load-balance loss reduce (deterministic, parallel) ----------------
__global__ __launch_bounds__(256) void lb_kernel(const float* __restrict__ part, float* __restrict__ outlb){
  __shared__ float sm[4][9];
  float acc[9] = {};
  for(int i=threadIdx.x; i<2048; i+=256){
#pragma unroll
    for(int c=0;c<9;c++) acc[c] += part[i*9+c];
  }
#pragma unroll
  for(int c=0;c<9;c++) acc[c] = wsum(acc[c]);
  int wv = threadIdx.x>>6, lane = threadIdx.x&63;
  if(lane==0){
#pragma unroll
    for(int c=0;c<9;c++) sm[wv][c]=acc[c];
  }
  __syncthreads();
  if(threadIdx.x==0){
    const float invN = 1.0f/(float)NTOK;
    float lb=0;
#pragma unroll
    for(int c=0;c<9;c++){
      float s = sm[0][c]+sm[1][c]+sm[2][c]+sm[3][c];
      float mw = s*invN;
      lb -= mw*logf(mw+1e-8f);
    }
    outlb[0] = lb*0.01f;
  }
}

// ---------------- bf16 MFMA GEMM: C[M,N] = epi(A[M,K] @ W[N,K]^T) ----------------
// MODE 0: store  2: rowv[m]*acc (+C if ADD)  3: resid+acc  4: C += BW*sigmoid(*gptr)*(resid+acc)
template<int MODE, int ADD>
__global__ __launch_bounds__(256) void gemm_mfma(
    const float* __restrict__ A, const float* __restrict__ W, float* __restrict__ C,
    int M, int N, int K,
    const float* __restrict__ sv, const float* __restrict__ bv,
    const float* __restrict__ rowv,
    const float* __restrict__ resid, const float* __restrict__ gptr){
  __shared__ unsigned short As[64*LDK];
  __shared__ unsigned short Ws[64*LDK];
  int tid  = threadIdx.x;
  int m0   = blockIdx.y*64, n0 = blockIdx.x*64;
  int w    = tid>>6, lane = tid&63;
  int wr   = (w>>1)*32, wc = (w&1)*32;
  int r    = tid>>2, seg = (tid&3)*16;
  f32x4 acc[2][2] = {};
  for(int k0=0;k0<K;k0+=64){
    __syncthreads();
    stage16(A + (size_t)(m0+r)*K + k0 + seg,
            sv ? sv+k0+seg : nullptr, sv ? bv+k0+seg : nullptr,
            &As[r*LDK + seg]);
    stage16(W + (size_t)(n0+r)*K + k0 + seg, nullptr, nullptr,
            &Ws[r*LDK + seg]);
    __syncthreads();
#pragma unroll
    for(int kk=0;kk<64;kk+=32){
      int ko = kk + (lane>>4)*8;
      bf16x8 a0 = *reinterpret_cast<const bf16x8*>(&As[(wr    + (lane&15))*LDK + ko]);
      bf16x8 a1 = *reinterpret_cast<const bf16x8*>(&As[(wr+16 + (lane&15))*LDK + ko]);
      bf16x8 b0 = *reinterpret_cast<const bf16x8*>(&Ws[(wc    + (lane&15))*LDK + ko]);
      bf16x8 b1 = *reinterpret_cast<const bf16x8*>(&Ws[(wc+16 + (lane&15))*LDK + ko]);
      acc[0][0] = __builtin_amdgcn_mfma_f32_16x16x32_bf16(a0,b0,acc[0][0],0,0,0);
      acc[0][1] = __builtin_amdgcn_mfma_f32_16x16x32_bf16(a0,b1,acc[0][1],0,0,0);
      acc[1][0] = __builtin_amdgcn_mfma_f32_16x16x32_bf16(a1,b0,acc[1][0],0,0,0);
      acc[1][1] = __builtin_amdgcn_mfma_f32_16x16x32_bf16(a1,b1,acc[1][1],0,0,0);
    }
  }
#pragma unroll
  for(int i=0;i<2;i++){
#pragma unroll
    for(int j=0;j<2;j++){
      int mb = m0 + wr + i*16 + (lane>>4)*4;
      int n  = n0 + wc + j*16 + (lane&15);
#pragma unroll
      for(int rg=0;rg<4;rg++){
        int m = mb + rg;
        float v = acc[i][j][rg];
        size_t o = (size_t)m*N + n;
        if(MODE==0){ C[o] = v; }
        else if(MODE==2){ float rr = rowv[m]*v; C[o] = ADD ? (C[o]+rr) : rr; }
        else if(MODE==3){ C[o] = resid[o] + v; }
        else if(MODE==4){
          float gs = (0.5f/3.0f)/(1.0f+expf(-gptr[0]));
          C[o] += gs*(resid[o]+v);
        }
      }
    }
  }
}

// ---------------- dual-W bf16 MFMA GEMM: C = silu(A@G^T) * (A@V^T) ----------------
__global__ __launch_bounds__(256) void gemm_dual(
    const float* __restrict__ A, const float* __restrict__ G, const float* __restrict__ V,
    float* __restrict__ C, int M, int N, int K,
    const float* __restrict__ sv, const float* __restrict__ bv){
  __shared__ unsigned short As[64*LDK];
  __shared__ unsigned short Gs[64*LDK];
  __shared__ unsigned short Vs[64*LDK];
  int tid  = threadIdx.x;
  int m0   = blockIdx.y*64, n0 = blockIdx.x*64;
  int w    = tid>>6, lane = tid&63;
  int wr   = (w>>1)*32, wc = (w&1)*32;
  int r    = tid>>2, seg = (tid&3)*16;
  f32x4 accg[2][2] = {};
  f32x4 accv[2][2] = {};
  for(int k0=0;k0<K;k0+=64){
    __syncthreads();
    stage16(A + (size_t)(m0+r)*K + k0 + seg,
            sv ? sv+k0+seg : nullptr, sv ? bv+k0+seg : nullptr,
            &As[r*LDK + seg]);
    stage16(G + (size_t)(n0+r)*K + k0 + seg, nullptr, nullptr, &Gs[r*LDK + seg]);
    stage16(V + (size_t)(n0+r)*K + k0 + seg, nullptr, nullptr, &Vs[r*LDK + seg]);
    __syncthreads();
#pragma unroll
    for(int kk=0;kk<64;kk+=32){
      int ko = kk + (lane>>4)*8;
      bf16x8 a0 = *reinterpret_cast<const bf16x8*>(&As[(wr    + (lane&15))*LDK + ko]);
      bf16x8 a1 = *reinterpret_cast<const bf16x8*>(&As[(wr+16 + (lane&15))*LDK + ko]);
      bf16x8 g0 = *reinterpret_cast<const bf16x8*>(&Gs[(wc    + (lane&15))*LDK + ko]);
      bf16x8 g1 = *reinterpret_cast<const bf16x8*>(&Gs[(wc+16 + (lane&15))*LDK + ko]);
      bf16x8 v0 = *reinterpret_cast<const bf16x8*>(&Vs[(wc    + (lane&15))*LDK + ko]);
      bf16x8 v1 = *reinterpret_cast<const bf16x8*>(&Vs[(wc+16 + (lane&15))*LDK + ko]);
      accg[0][0] = __builtin_amdgcn_mfma_f32_16x16x32_bf16(a0,g0,accg[0][0],0,0,0);
      accg[0][1] = __builtin_amdgcn_mfma_f32_16x16x32_bf16(a0,g1,accg[0][1],0,0,0);
      accg[1][0] = __builtin_amdgcn_mfma_f32_16x16x32_bf16(a1,g0,accg[1][0],0,0,0);
      accg[1][1] = __builtin_amdgcn_mfma_f32_16x16x32_bf16(a1,g1,accg[1][1],0,0,0);
      accv[0][0] = __builtin_amdgcn_mfma_f32_16x16x32_bf16(a0,v0,accv[0][0],0,0,0);
      accv[0][1] = __builtin_amdgcn_mfma_f32_16x16x32_bf16(a0,v1,accv[0][1],0,0,0);
      accv[1][0] = __builtin_amdgcn_mfma_f32_16x16x32_bf16(a1,v0,accv[1][0],0,0,0);
      accv[1][1] = __builtin_amdgcn_mfma_f32_16x16x32_bf16(a1,v1,accv[1][1],0,0,0);
    }
  }
#pragma unroll
  for(int i=0;i<2;i++){
#pragma unroll
    for(int j=0;j<2;j++){
      int mb = m0 + wr + i*16 + (lane>>4)*4;
      int n  = n0 + wc + j*16 + (lane&15);
#pragma unroll
      for(int rg=0;rg<4;rg++){
        float gg = accg[i][j][rg];
        float vv = accv[i][j][rg];
        float sg = gg/(1.0f+expf(-gg));
        C[(size_t)(mb+rg)*N + n] = sg*vv;
      }
    }
  }
}

// ---------------- fused MFMA flash attention ----------------
// Block = 4 waves; wave handles 16 q-rows; block covers 64 q-rows of one (b,h).
// K tile: 64 keys staged bf16 [64][40]; V staged transposed [32][72]; per-wave P tile [16][72].
// Fragment convention identical to gemm_mfma (validated): A row=lane&15, k=(lane>>4)*8+e;
// B = weight-layout rows (output col = lane&15); C col=lane&15, row=(lane>>4)*4+reg.
__global__ __launch_bounds__(256) void attn_fused(
    const float* __restrict__ Qb, const float* __restrict__ KVb,
    float* __restrict__ O){
  __shared__ __align__(16) unsigned short Ks[64*40];
  __shared__ __align__(16) unsigned short Vt[32*72];
  __shared__ __align__(16) unsigned short Ps[4][16*72];
  const int tid = threadIdx.x;
  const int w = tid>>6, lane = tid&63;
  const int lr = lane&15, lg = lane>>4;
  const int bx = blockIdx.x, h = blockIdx.y, b = blockIdx.z;
  const float scale = 0.17677669529663687f;   // 1/sqrt(32)
  // Q fragment (A-layout), scale folded before bf16 conversion
  const int qtok0 = b*TT + bx*64 + w*16;
  const float* qp = Qb + (size_t)(qtok0 + lr)*DD + h*HDD + lg*8;
  float4 qf0 = *reinterpret_cast<const float4*>(qp);
  float4 qf1 = *reinterpret_cast<const float4*>(qp+4);
  __align__(16) unsigned short qh[8] = {
    f2bf(qf0.x*scale),f2bf(qf0.y*scale),f2bf(qf0.z*scale),f2bf(qf0.w*scale),
    f2bf(qf1.x*scale),f2bf(qf1.y*scale),f2bf(qf1.z*scale),f2bf(qf1.w*scale)};
  bf16x8 qa = *reinterpret_cast<const bf16x8*>(qh);
  f32x4 o0 = {}, o1 = {};
  float m[4]    = {-1e30f,-1e30f,-1e30f,-1e30f};
  float lsum[4] = {};
  const float* KVbase = KVb + (size_t)(b*TT)*(2*DD) + h*HDD;

  for(int t0=0; t0<TT; t0+=64){
    __syncthreads();
    // stage K (row-major bf16) and V (transposed bf16)
#pragma unroll
    for(int s2=0;s2<2;s2++){
      int i   = tid + s2*256;
      int key = i>>3, seg = (i&7)*4;
      const float* src = KVbase + (size_t)(t0+key)*(2*DD) + seg;
      float4 kk = *reinterpret_cast<const float4*>(src);
      unsigned short kh4[4] = {f2bf(kk.x),f2bf(kk.y),f2bf(kk.z),f2bf(kk.w)};
      *reinterpret_cast<uint2*>(&Ks[key*40+seg]) = *reinterpret_cast<uint2*>(kh4);
      float4 vv = *reinterpret_cast<const float4*>(src + DD);
      Vt[(seg  )*72+key] = f2bf(vv.x);
      Vt[(seg+1)*72+key] = f2bf(vv.y);
      Vt[(seg+2)*72+key] = f2bf(vv.z);
      Vt[(seg+3)*72+key] = f2bf(vv.w);
    }
    __syncthreads();
    // QK^T: 4 MFMAs -> scores for 16q x 64k
    f32x4 s[4];
#pragma unroll
    for(int f=0;f<4;f++){
      bf16x8 kb = *reinterpret_cast<const bf16x8*>(&Ks[(f*16+lr)*40 + lg*8]);
      f32x4 z = {};
      s[f] = __builtin_amdgcn_mfma_f32_16x16x32_bf16(qa,kb,z,0,0,0);
    }
    // online softmax per C-row (reg r), reduce across 16-lane subgroup
#pragma unroll
    for(int r=0;r<4;r++){
      float tmax = fmaxf(fmaxf(s[0][r],s[1][r]),fmaxf(s[2][r],s[3][r]));
#pragma unroll
      for(int off=1;off<16;off<<=1) tmax = fmaxf(tmax,__shfl_xor(tmax,off,64));
      float nm = fmaxf(m[r],tmax);
      float sc = __expf(m[r]-nm);
      m[r] = nm; lsum[r] *= sc; o0[r] *= sc; o1[r] *= sc;
      float ps = 0.f;
#pragma unroll
      for(int f=0;f<4;f++){
        float p = __expf(s[f][r]-nm);
        ps += p;
        Ps[w][(lg*4+r)*72 + f*16 + lr] = f2bf(p);
      }
#pragma unroll
      for(int off=1;off<16;off<<=1) ps += __shfl_xor(ps,off,64);
      lsum[r] += ps;
    }
    // PV: O[16q,32d] += P[16q,64k] @ V[64k,32d]  (B = Vt weight-layout)
    bf16x8 pa0 = *reinterpret_cast<const bf16x8*>(&Ps[w][lr*72 + lg*8]);
    bf16x8 pa1 = *reinterpret_cast<const bf16x8*>(&Ps[w][lr*72 + lg*8 + 32]);
    {
      bf16x8 vb0 = *reinterpret_cast<const bf16x8*>(&Vt[(lr)*72 + lg*8]);
      bf16x8 vb1 = *reinterpret_cast<const bf16x8*>(&Vt[(lr)*72 + lg*8 + 32]);
      o0 = __builtin_amdgcn_mfma_f32_16x16x32_bf16(pa0,vb0,o0,0,0,0);
      o0 = __builtin_amdgcn_mfma_f32_16x16x32_bf16(pa1,vb1,o0,0,0,0);
    }
    {
      bf16x8 vb0 = *reinterpret_cast<const bf16x8*>(&Vt[(16+lr)*72 + lg*8]);
      bf16x8 vb1 = *reinterpret_cast<const bf16x8*>(&Vt[(16+lr)*72 + lg*8 + 32]);
      o1 = __builtin_amdgcn_mfma_f32_16x16x32_bf16(pa0,vb0,o1,0,0,0);
      o1 = __builtin_amdgcn_mfma_f32_16x16x32_bf16(pa1,vb1,o1,0,0,0);
    }
  }
  // normalize + write
#pragma unroll
  for(int r=0;r<4;r++){
    float inv = 1.0f/lsum[r];
    int row = qtok0 + lg*4 + r;
    float* orow = O + (size_t)row*DD + h*HDD;
    orow[lr]      = o0[r]*inv;
    orow[16+lr]   = o1[r]*inv;
  }
}

__global__ __launch_bounds__(256) void add3_kernel(const float* __restrict__ a,
                                                   const float* __restrict__ b,
                                                   const float* __restrict__ c,
                                                   float* __restrict__ out, int n){
  int i = blockIdx.x*256 + threadIdx.x;
  if(i<n) out[i] = a[i]+b[i]+c[i];
}

// ---------------- launch ----------------
extern "C" void kernel_launch(void* const* d_in, const int* in_sizes, int n_in,
                              void* d_out, int out_size, void* d_ws, size_t ws_size,
                              hipStream_t stream){
  (void)in_sizes; (void)n_in; (void)out_size; (void)ws_size;
  const float* x       = (const float*)d_in[0];
  const float* gr_g    = (const float*)d_in[1];
  const float* gr_b    = (const float*)d_in[2];
  const float* q6_w    = (const float*)d_in[3];
  const float* logtemp = (const float*)d_in[4];
  const float* grp_g   = (const float*)d_in[5];
  const float* grp_b   = (const float*)d_in[6];
  const float* gpw     = (const float*)d_in[7];
  const float* gpb     = (const float*)d_in[8];
  const float* me_g    = (const float*)d_in[9];
  const float* me_b    = (const float*)d_in[10];
  const float* me_gate = (const float*)d_in[11];
  const float* me_val  = (const float*)d_in[12];
  const float* me_out  = (const float*)d_in[13];
  const float* br_in   = (const float*)d_in[14];
  const float* br_outw = (const float*)d_in[15];
  const float* nq_g    = (const float*)d_in[16];
  const float* nq_b    = (const float*)d_in[17];
  const float* nkv_g   = (const float*)d_in[18];
  const float* nkv_b   = (const float*)d_in[19];
  const float* nff_g   = (const float*)d_in[20];
  const float* nff_b   = (const float*)d_in[21];
  const float* brg_w   = (const float*)d_in[22];
  const float* brv_w   = (const float*)d_in[23];
  const float* brf_w   = (const float*)d_in[24];
  const float* br_gate = (const float*)d_in[25];
  const float* on_g    = (const float*)d_in[26];
  const float* on_b    = (const float*)d_in[27];
  const float* out_w   = (const float*)d_in[28];
  float* out = (float*)d_out;
  float* ws  = (float*)d_ws;

  float* xn    = ws;                 // 1048576
  float* gw    = ws + 1048576;       // 24576
  float* coef  = ws + 1073152;       // 49152
  float* part  = ws + 1122304;       // 18432
  float* gvb   = ws + 3237888;       // 2097152
  float* go    = ws + 5335040;       // 3*1048576
  float* qn    = ws + 8480768;       // 1048576
  float* kvn   = ws + 9529344;       // 1048576
  float* Qb    = ws + 10577920;      // 1048576
  float* KVb   = ws + 11626496;      // 2097152
  float* obuf  = ws + 18180096;      // 1048576
  float* xb    = ws + 19228672;      // 1048576
  float* hb    = ws + 20277248;      // 1048576
  float* comb  = ws + 21325824;      // 1048576

  // 1. xn (plain normalize) + routing + lb
  ln_kernel<<<2048,256,0,stream>>>(x, xn, nullptr, nullptr);
  routing_kernel<<<2048,256,0,stream>>>(xn, gr_g, gr_b, q6_w, logtemp,
                                        grp_g, grp_b, gpw, gpb, gw, coef, part);
  lb_kernel<<<1,256,0,stream>>>(part, out + 1048576);

  // 2. MoE experts -> group_outs (go)
  for(int e=0;e<6;e++){
    gemm_dual<<<dim3(4,128),256,0,stream>>>(xn,
        me_gate + (size_t)e*DFF*DD, me_val + (size_t)e*DFF*DD, gvb,
        NTOK,DFF,DD, me_g+e*DD, me_b+e*DD);
    float* gout = go + (size_t)(e>>1)*NTOK*DD;
    if(e&1)
      gemm_mfma<2,1><<<dim3(2,128),256,0,stream>>>(gvb, me_out + (size_t)e*DD*DFF, gout,
          NTOK,DD,DFF, nullptr,nullptr, coef+(size_t)e*NTOK, nullptr,nullptr);
    else
      gemm_mfma<2,0><<<dim3(2,128),256,0,stream>>>(gvb, me_out + (size_t)e*DD*DFF, gout,
          NTOK,DD,DFF, nullptr,nullptr, coef+(size_t)e*NTOK, nullptr,nullptr);
  }

  // 3. combined = go0+go1+go2
  add3_kernel<<<4096,256,0,stream>>>(go, go+(size_t)NTOK*DD, go+(size_t)2*NTOK*DD, comb, NTOK*DD);

  // 4. bridges
  const int pairs[3][2] = {{0,1},{1,2},{0,2}};
  for(int i=0;i<3;i++){
    const float* xq = go + (size_t)pairs[i][0]*NTOK*DD;
    const float* xk = go + (size_t)pairs[i][1]*NTOK*DD;
    ln_kernel<<<2048,256,0,stream>>>(xq, qn,  nq_g+i*DD,  nq_b+i*DD);
    ln_kernel<<<2048,256,0,stream>>>(xk, kvn, nkv_g+i*DD, nkv_b+i*DD);
    gemm_mfma<0,0><<<dim3(2,128),256,0,stream>>>(qn,  br_in + (size_t)i*3*DD*DD, Qb,
        NTOK,DD,DD, nullptr,nullptr,nullptr,nullptr,nullptr);
    gemm_mfma<0,0><<<dim3(4,128),256,0,stream>>>(kvn, br_in + (size_t)i*3*DD*DD + DD*DD, KVb,
        NTOK,2*DD,DD, nullptr,nullptr,nullptr,nullptr,nullptr);
    attn_fused<<<dim3(16,NHH,BB),256,0,stream>>>(Qb, KVb, obuf);
    gemm_mfma<3,0><<<dim3(2,128),256,0,stream>>>(obuf, br_outw + (size_t)i*DD*DD, xb,
        NTOK,DD,DD, nullptr,nullptr,nullptr, xq, nullptr);
    ln_kernel<<<2048,256,0,stream>>>(xb, hb, nff_g+i*DD, nff_b+i*DD);
    gemm_dual<<<dim3(4,128),256,0,stream>>>(hb,
        brg_w + (size_t)i*2*DD*DD, brv_w + (size_t)i*2*DD*DD, gvb,
        NTOK,2*DD,DD, nullptr,nullptr);
    gemm_mfma<4,0><<<dim3(2,128),256,0,stream>>>(gvb, brf_w + (size_t)i*DD*2*DD, comb,
        NTOK,DD,2*DD, nullptr,nullptr,nullptr, xb, br_gate+i);
  }

  // 5. final LN + projection
  ln_kernel<<<2048,256,0,stream>>>(comb, hb, on_g, on_b);
  gemm_mfma<0,0><<<dim3(2,128),256,0,stream>>>(hb, out_w, out,
      NTOK,DD,DD, nullptr,nullptr,nullptr,nullptr,nullptr);
}